// Round 10
// baseline (322.870 us; speedup 1.0000x reference)
//
#include <hip/hip_runtime.h>
#include <hip/hip_bf16.h>
#include <stdint.h>

// ---------------------------------------------------------------------------
// TransformerDecoderBlock on MI355X (gfx950).  B=2, T=2048, C=1024, H=16, hd=64.
// R16: 307.8us -- gemm256_k 8-phase (counted vmcnt + setprio + 8-wave
//      role-split) for qkv/FF1; gemm6464_k (drain-0, 16 waves) for Wo/FF2.
// R17: gemm128p_k (128^2 phase-sched) NEUTRAL-loss: 8-MFMA phases too thin.
//      Reverted; phase schedule pays only with 16-MFMA clusters.
// R18: FF2 split-K4 via the PROVEN gemm256_k (PART mode: f32 partials at
//      z*M*N, no bias) + reduce4_k (sum + bias + resid, proven R12).
//      Grid (4,16,4) = 256 blocks = 1/CU, per-block work == FF1's blocks.
//      Breaks the 64^2 structure's ~41us LDS floor. Wo back on gemm6464_k.
// ---------------------------------------------------------------------------

typedef __attribute__((ext_vector_type(8))) short bf16x8;   // 8 bf16 in 4 VGPRs
typedef __attribute__((ext_vector_type(4))) float f32x4;

#define MFMA16(a, b, c) __builtin_amdgcn_mfma_f32_16x16x32_bf16((a), (b), (c), 0, 0, 0)

__device__ __forceinline__ void gload16(const void* g, void* l) {
    __builtin_amdgcn_global_load_lds(
        (const __attribute__((address_space(1))) char*)g,
        (__attribute__((address_space(3))) char*)l, 16, 0, 0);
}

// XCD-aware remap: contiguous chunk of work per XCD (XCD = dispatch id % 8).
__device__ __forceinline__ int xcd_swizzle(int flat, int nblk) {
    if ((nblk & 7) == 0) {
        const int per = nblk >> 3;
        flat = (flat & 7) * per + (flat >> 3);
    }
    return flat;
}

// ---------------- merged transpose + fp32->bf16 for all 4 weights -----------
__global__ __launch_bounds__(256) void tconv_all(
    const float* __restrict__ w0, __hip_bfloat16* __restrict__ o0,   // 1024x3072
    const float* __restrict__ w1, __hip_bfloat16* __restrict__ o1,   // 1024x1024
    const float* __restrict__ w2, __hip_bfloat16* __restrict__ o2,   // 1024x4096
    const float* __restrict__ w3, __hip_bfloat16* __restrict__ o3) { // 4096x1024
    __shared__ float tile[64][33];                  // [k][n]
    const int f = blockIdx.x;
    const float* in; __hip_bfloat16* out; int K, N, nx, t;
    if (f < 1536)      { in = w0; out = o0; K = 1024; N = 3072; nx = 96;  t = f; }
    else if (f < 2048) { in = w1; out = o1; K = 1024; N = 1024; nx = 32;  t = f - 1536; }
    else if (f < 4096) { in = w2; out = o2; K = 1024; N = 4096; nx = 128; t = f - 2048; }
    else               { in = w3; out = o3; K = 4096; N = 1024; nx = 32;  t = f - 4096; }
    const int n0 = (t % nx) * 32, k0 = (t / nx) * 64;
    const int tx = threadIdx.x, ty = threadIdx.y;   // block (32, 8)
#pragma unroll
    for (int i = 0; i < 8; i++)
        tile[i * 8 + ty][tx] = in[(size_t)(k0 + i * 8 + ty) * N + n0 + tx];
    __syncthreads();
    for (int i = ty; i < 32; i += 8) {
        const unsigned short lo =
            __bfloat16_as_ushort(__float2bfloat16(tile[2 * tx][i]));
        const unsigned short hi =
            __bfloat16_as_ushort(__float2bfloat16(tile[2 * tx + 1][i]));
        *(uint32_t*)(out + (size_t)(n0 + i) * K + k0 + 2 * tx) =
            ((uint32_t)hi << 16) | lo;
    }
}

// --------------------------------- layernorm -------------------------------
__global__ __launch_bounds__(256) void ln_k(const float* __restrict__ x,
                                            const float* __restrict__ g,
                                            const float* __restrict__ beta,
                                            __hip_bfloat16* __restrict__ out) {
    const int row = blockIdx.x;
    const int tid = threadIdx.x;
    float4 v = ((const float4*)(x + (size_t)row * 1024))[tid];
    float s  = v.x + v.y + v.z + v.w;
    float s2 = v.x * v.x + v.y * v.y + v.z * v.z + v.w * v.w;
    for (int off = 1; off < 64; off <<= 1) {
        s  += __shfl_xor(s,  off, 64);
        s2 += __shfl_xor(s2, off, 64);
    }
    __shared__ float ss[4], ss2[4];
    const int w = tid >> 6, lane = tid & 63;
    if (lane == 0) { ss[w] = s; ss2[w] = s2; }
    __syncthreads();
    s  = ss[0] + ss[1] + ss[2] + ss[3];
    s2 = ss2[0] + ss2[1] + ss2[2] + ss2[3];
    const float mu  = s * (1.0f / 1024.0f);
    const float var = s2 * (1.0f / 1024.0f) - mu * mu;
    const float rs  = rsqrtf(var + 1e-5f);
    float4 gv = ((const float4*)g)[tid];
    float4 bv = ((const float4*)beta)[tid];
    __hip_bfloat16* o = out + (size_t)row * 1024 + tid * 4;
    o[0] = __float2bfloat16((v.x - mu) * rs * gv.x + bv.x);
    o[1] = __float2bfloat16((v.y - mu) * rs * gv.y + bv.y);
    o[2] = __float2bfloat16((v.z - mu) * rs * gv.z + bv.z);
    o[3] = __float2bfloat16((v.w - mu) * rs * gv.w + bv.w);
}

// ----------- 8-phase GEMM, BM=BN=256 BK=64, 512 threads, 2x4 waves ----------
// [R16 proven] PART=1: split-K partial mode -- blockIdx.z selects the K-span
// (z*kper), output = f32 partial at z*M*N, no bias/relu.
template <int BIAS, int RELU, int PART>
__global__ __launch_bounds__(512, 2) void gemm256_k(const __hip_bfloat16* __restrict__ A,
                                                    const __hip_bfloat16* __restrict__ Bt,
                                                    const float* __restrict__ bias,
                                                    void* __restrict__ out,
                                                    int M, int N, int K, int kper) {
    __align__(16) __shared__ __hip_bfloat16 As[2][2][128 * 64];  // [dbuf][half]
    __align__(16) __shared__ __hip_bfloat16 Bs[2][2][128 * 64];

    const int tid  = threadIdx.x;
    const int lane = tid & 63, w = tid >> 6;        // 8 waves
    const int wm = w >> 2, wn = w & 3;              // 2(M) x 4(N)
    const int nbx = gridDim.x;
    const int flat = xcd_swizzle(blockIdx.y * nbx + blockIdx.x, nbx * gridDim.y);
    const int m0 = (flat / nbx) * 256, n0 = (flat % nbx) * 256;
    const int z  = blockIdx.z;
    const int l16 = lane & 15, quad = lane >> 4;

    const int srw = lane >> 3;                 // 0..7
    const int scn = ((lane & 7) - srw) & 7;    // swizzled source chunk

    const __hip_bfloat16* gA[2][2];
    const __hip_bfloat16* gB[2][2];
#pragma unroll
    for (int h = 0; h < 2; h++)
#pragma unroll
        for (int i = 0; i < 2; i++) {
            const int r = h * 128 + i * 64 + w * 8 + srw;
            gA[h][i] = A  + (size_t)(m0 + r) * K + (size_t)z * kper + scn * 8;
            gB[h][i] = Bt + (size_t)(n0 + r) * K + (size_t)z * kper + scn * 8;
        }

    int offA[2][4], offB[2][2];
#pragma unroll
    for (int s = 0; s < 2; s++) {
#pragma unroll
        for (int t = 0; t < 4; t++) {
            const int r = t * 16 + l16;
            offA[s][t] = (r * 8 + ((s * 4 + quad + (r & 7)) & 7)) * 16;
        }
#pragma unroll
        for (int t = 0; t < 2; t++) {
            const int r = (wn & 1) * 64 + t * 16 + l16;
            offB[s][t] = (r * 8 + ((s * 4 + quad + (r & 7)) & 7)) * 16;
        }
    }
    const char* AsW = (const char*)&As[0][wm][0];       // +D*32768 +MH*8192
    const char* BsW = (const char*)&Bs[0][wn >> 1][0];  // +D*32768 +NH*4096

    f32x4 acc[8][4] = {};
    bf16x8 a[2][4], b[2][2];

    const int NT = kper >> 6;   // 16 for all uses

#define STG_A(ST, SH, D)                                                      \
    do { if ((ST) < NT) {                                                     \
        _Pragma("unroll") for (int i = 0; i < 2; i++)                         \
            gload16(gA[SH][i] + (size_t)(ST) * 64,                            \
                    &As[D][SH][(i * 64 + w * 8) * 64]);                       \
    } } while (0)
#define STG_B(ST, SH, D)                                                      \
    do { if ((ST) < NT) {                                                     \
        _Pragma("unroll") for (int i = 0; i < 2; i++)                         \
            gload16(gB[SH][i] + (size_t)(ST) * 64,                            \
                    &Bs[D][SH][(i * 64 + w * 8) * 64]);                       \
    } } while (0)
#define VM_NONE do {} while (0)
#define VM_P(X)                                                               \
    do { if ((X) < NT) asm volatile("s_waitcnt vmcnt(2)" ::: "memory");       \
         else          asm volatile("s_waitcnt vmcnt(0)" ::: "memory");       \
    } while (0)

#define PH(RDA, MH, RDB, NH, D, STG, VM)                                      \
    do {                                                                      \
        if (RDA) {                                                            \
            _Pragma("unroll") for (int s = 0; s < 2; s++)                     \
            _Pragma("unroll") for (int t = 0; t < 4; t++)                     \
                a[s][t] = *(const bf16x8*)(AsW + (D) * 32768 + (MH) * 8192 +  \
                                           offA[s][t]);                       \
        }                                                                     \
        if (RDB) {                                                            \
            _Pragma("unroll") for (int s = 0; s < 2; s++)                     \
            _Pragma("unroll") for (int t = 0; t < 2; t++)                     \
                b[s][t] = *(const bf16x8*)(BsW + (D) * 32768 + (NH) * 4096 +  \
                                           offB[s][t]);                       \
        }                                                                     \
        STG;                                                                  \
        __builtin_amdgcn_s_barrier();                                         \
        asm volatile("" ::: "memory");                                        \
        __builtin_amdgcn_s_setprio(1);                                        \
        _Pragma("unroll") for (int s = 0; s < 2; s++)                         \
        _Pragma("unroll") for (int ti = 0; ti < 4; ti++)                      \
        _Pragma("unroll") for (int tj = 0; tj < 2; tj++)                      \
            acc[(MH) * 4 + ti][(NH) * 2 + tj] =                               \
                MFMA16(a[s][ti], b[s][tj], acc[(MH) * 4 + ti][(NH) * 2 + tj]);\
        __builtin_amdgcn_s_setprio(0);                                        \
        VM;                                                                   \
        __builtin_amdgcn_s_barrier();                                         \
        asm volatile("" ::: "memory");                                        \
    } while (0)

    STG_A(0, 0, 0); STG_A(0, 1, 0); STG_B(0, 0, 0); STG_B(0, 1, 0);
    STG_A(1, 0, 1);
    asm volatile("s_waitcnt vmcnt(2)" ::: "memory");
    __builtin_amdgcn_s_barrier();
    asm volatile("" ::: "memory");

    for (int T = 0; T < NT; T += 2) {
        PH(1, 0, 1, 0, 0, STG_A(T + 1, 1, 1), VM_NONE);     // p0: q(0,0)
        PH(0, 0, 1, 1, 0, STG_B(T + 1, 0, 1), VM_NONE);     // p1: q(0,1)
        PH(1, 1, 0, 1, 0, STG_B(T + 1, 1, 1), VM_NONE);     // p2: q(1,1)
        PH(0, 1, 1, 0, 0, STG_A(T + 2, 0, 0), VM_P(T + 2)); // p3: q(1,0)
        PH(1, 0, 1, 0, 1, STG_A(T + 2, 1, 0), VM_NONE);     // p4: q(0,0)
        PH(0, 0, 1, 1, 1, STG_B(T + 2, 0, 0), VM_NONE);     // p5: q(0,1)
        PH(1, 1, 0, 1, 1, STG_B(T + 2, 1, 0), VM_NONE);     // p6: q(1,1)
        PH(0, 1, 1, 0, 1, STG_A(T + 3, 0, 1), VM_P(T + 3)); // p7: q(1,0)
    }
#undef PH
#undef VM_P
#undef VM_NONE
#undef STG_B
#undef STG_A

#pragma unroll
    for (int mt = 0; mt < 8; mt++)
#pragma unroll
        for (int nt = 0; nt < 4; nt++) {
            const int row = m0 + wm * 128 + mt * 16 + quad * 4;
            const int col = n0 + wn * 64 + nt * 16 + l16;
            const float bv = (BIAS && !PART) ? bias[col] : 0.0f;
#pragma unroll
            for (int r = 0; r < 4; r++) {
                float v = acc[mt][nt][r] + bv;
                if (RELU) v = v > 0.0f ? v : 0.0f;
                const size_t idx = (size_t)(row + r) * N + col;
                if (PART) ((float*)out)[(size_t)z * M * N + idx] = v;
                else ((__hip_bfloat16*)out)[idx] = __float2bfloat16(v);
            }
        }
}

// ------------- split-K reduce: out = sum(parts) + bias + resid (f32) --------
__global__ __launch_bounds__(256) void reduce4_k(const float* __restrict__ parts,
                                                 const float* __restrict__ bias,
                                                 const float* __restrict__ resid,
                                                 float* __restrict__ out) {
    const size_t f = (size_t)blockIdx.x * 256 + threadIdx.x;   // float4 index
    const size_t STRIDE = 4096ULL * 1024 / 4;                  // 1M float4
    float4 a = ((const float4*)parts)[f];
    float4 b = ((const float4*)parts)[f + STRIDE];
    float4 c = ((const float4*)parts)[f + 2 * STRIDE];
    float4 d = ((const float4*)parts)[f + 3 * STRIDE];
    float4 rv = ((const float4*)resid)[f];
    float4 bv = ((const float4*)bias)[f & 255];                // N/4 = 256
    float4 o;
    o.x = a.x + b.x + c.x + d.x + rv.x + bv.x;
    o.y = a.y + b.y + c.y + d.y + rv.y + bv.y;
    o.z = a.z + b.z + c.z + d.z + rv.z + bv.z;
    o.w = a.w + b.w + c.w + d.w + rv.w + bv.w;
    ((float4*)out)[f] = o;
}

// ------------------- GEMM, BM=64 BN=64 BK=64, dbuf 1-barrier -----------------
// For Wo (N=1024, K=1024): grid 16x64 = 1024 blocks -> 4 blocks/CU. [proven]
template <int BIAS, int RELU, int RESID, int OUTBF>
__global__ __launch_bounds__(256, 4) void gemm6464_k(const __hip_bfloat16* __restrict__ A,
                                                     const __hip_bfloat16* __restrict__ Bt,
                                                     const float* __restrict__ bias,
                                                     const float* __restrict__ resid,
                                                     void* __restrict__ out,
                                                     int M, int N, int K) {
    __align__(16) __shared__ __hip_bfloat16 As[2][64 * 64];
    __align__(16) __shared__ __hip_bfloat16 Bs[2][64 * 64];

    const int tid  = threadIdx.x;
    const int lane = tid & 63, w = tid >> 6;
    const int wm = w >> 1, wn = w & 1;             // 2x2 wave grid of 32x32
    const int nbx = gridDim.x;
    const int flat = xcd_swizzle(blockIdx.y * nbx + blockIdx.x, nbx * gridDim.y);
    const int m0 = (flat / nbx) * 64, n0 = (flat % nbx) * 64;
    const int l16 = lane & 15, quad = lane >> 4;

    const int srw = lane >> 3;
    const int scn = ((lane & 7) - srw) & 7;

    const __hip_bfloat16* ga[2];
    const __hip_bfloat16* gb[2];
#pragma unroll
    for (int i = 0; i < 2; i++) {
        const int row = i * 32 + w * 8 + srw;
        ga[i] = A  + (size_t)(m0 + row) * K + scn * 8;
        gb[i] = Bt + (size_t)(n0 + row) * K + scn * 8;
    }

    int offA[2][2], offB[2][2];
#pragma unroll
    for (int s = 0; s < 2; s++)
#pragma unroll
        for (int t = 0; t < 2; t++) {
            const int rA = wm * 32 + t * 16 + l16;
            offA[s][t] = (rA * 8 + ((s * 4 + quad + (rA & 7)) & 7)) * 16;
            const int rB = wn * 32 + t * 16 + l16;
            offB[s][t] = (rB * 8 + ((s * 4 + quad + (rB & 7)) & 7)) * 16;
        }

    f32x4 acc[2][2] = {};

#pragma unroll
    for (int i = 0; i < 2; i++) {
        gload16(ga[i], As[0] + (i * 256 + w * 64) * 8);
        gload16(gb[i], Bs[0] + (i * 256 + w * 64) * 8);
        ga[i] += 64; gb[i] += 64;
    }

    const int niter = K >> 6;
    for (int it = 0; it < niter; it++) {
        const int buf = it & 1;
        __syncthreads();   // drains prefetch into buf
        if (it + 1 < niter) {
#pragma unroll
            for (int i = 0; i < 2; i++) {
                gload16(ga[i], As[buf ^ 1] + (i * 256 + w * 64) * 8);
                gload16(gb[i], Bs[buf ^ 1] + (i * 256 + w * 64) * 8);
                ga[i] += 64; gb[i] += 64;
            }
        }

#pragma unroll
        for (int s = 0; s < 2; s++) {
            bf16x8 af[2], bfr[2];
#pragma unroll
            for (int t = 0; t < 2; t++) {
                af[t]  = *(const bf16x8*)((const char*)As[buf] + offA[s][t]);
                bfr[t] = *(const bf16x8*)((const char*)Bs[buf] + offB[s][t]);
            }
#pragma unroll
            for (int mt = 0; mt < 2; mt++)
#pragma unroll
                for (int nt = 0; nt < 2; nt++)
                    acc[mt][nt] = MFMA16(af[mt], bfr[nt], acc[mt][nt]);
        }
    }

#pragma unroll
    for (int mt = 0; mt < 2; mt++)
#pragma unroll
        for (int nt = 0; nt < 2; nt++) {
            const int row = m0 + wm * 32 + mt * 16 + quad * 4;
            const int col = n0 + wn * 32 + nt * 16 + l16;
            const float bv = BIAS ? bias[col] : 0.0f;
#pragma unroll
            for (int r = 0; r < 4; r++) {
                float v = acc[mt][nt][r] + bv;
                if (RELU) v = v > 0.0f ? v : 0.0f;
                const size_t idx = (size_t)(row + r) * N + col;
                if (RESID) v += resid[idx];
                if (OUTBF) ((__hip_bfloat16*)out)[idx] = __float2bfloat16(v);
                else       ((float*)out)[idx] = v;
            }
        }
}

// ----------------------- V transpose: qkv -> Vt[bh][d][T] -------------------
__global__ __launch_bounds__(256) void vtrans_k(const __hip_bfloat16* __restrict__ qkv,
                                                __hip_bfloat16* __restrict__ vt) {
    const int T = 2048, C3 = 3072;
    const int bh = blockIdx.y, b = bh >> 4, h = bh & 15;
    const int t0 = blockIdx.x * 64;
    const int tx = threadIdx.x, ty = threadIdx.y;   // block (64, 4)
    __shared__ __hip_bfloat16 tile[64][65];
#pragma unroll
    for (int j = 0; j < 16; j++) {
        const int tl = ty * 16 + j;
        tile[tl][tx] = qkv[(size_t)(b * T + t0 + tl) * C3 + 2048 + h * 64 + tx];
    }
    __syncthreads();
#pragma unroll
    for (int j = 0; j < 16; j++) {
        const int d = ty * 16 + j;
        vt[((size_t)bh * 64 + d) * 2048 + t0 + tx] = tile[tx][d];
    }
}

// ------------------------------ flash attention -----------------------------
__global__ __launch_bounds__(256, 3) void attn_k(const __hip_bfloat16* __restrict__ qkv,
                                                 const __hip_bfloat16* __restrict__ vt,
                                                 __hip_bfloat16* __restrict__ outp) {
    const int T = 2048, C3 = 3072;
    const int bh = blockIdx.x, b = bh >> 4, h = bh & 15;
    const int qt = 31 - blockIdx.y;           // heavy q-tiles dispatched first
    const int q0 = qt * 64;
    const int tid = threadIdx.x, lane = tid & 63, w = tid >> 6;
    const int l16 = lane & 15, quad = lane >> 4;

    __align__(16) __shared__ __hip_bfloat16 Ks[2][64 * 64];   // swizzled [key][d]
    __align__(16) __shared__ __hip_bfloat16 Vs[2][64 * 64];   // swizzled [d][key]
    __align__(16) __shared__ __hip_bfloat16 Pw[4][16 * 72];   // per-wave P

    const float sc = 0.125f * 1.44269504f;
    bf16x8 qf0, qf1;
    {
        const __hip_bfloat16* qp =
            qkv + (size_t)(b * T + q0 + w * 16 + l16) * C3 + h * 64;
        bf16x8 a = *(const bf16x8*)(qp + quad * 8);
        bf16x8 c = *(const bf16x8*)(qp + 32 + quad * 8);
#pragma unroll
        for (int i = 0; i < 8; i++) {
            union { unsigned int u; float f; } ua, uc;
            ua.u = ((unsigned int)(unsigned short)a[i]) << 16;
            uc.u = ((unsigned int)(unsigned short)c[i]) << 16;
            qf0[i] = (short)(__bfloat16_as_ushort(__float2bfloat16(ua.f * sc)));
            qf1[i] = (short)(__bfloat16_as_ushort(__float2bfloat16(uc.f * sc)));
        }
    }

    const int srw = lane >> 3;
    const int scn = ((lane & 7) - srw) & 7;
    const __hip_bfloat16* kp[2];
    const __hip_bfloat16* vp[2];
#pragma unroll
    for (int i = 0; i < 2; i++) {
        const int row = i * 32 + w * 8 + srw;
        kp[i] = qkv + (size_t)(b * T + row) * C3 + 1024 + h * 64 + scn * 8;
        vp[i] = vt + ((size_t)bh * 64 + row) * 2048 + scn * 8;
    }

    int offK[2][4];
#pragma unroll
    for (int s = 0; s < 2; s++)
#pragma unroll
        for (int t = 0; t < 4; t++) {
            const int rr = t * 16 + l16;
            offK[s][t] = (rr * 8 + ((s * 4 + quad + (rr & 7)) & 7)) * 16;
        }

    f32x4 oacc[4] = {};
    float lpart[4] = {0.0f, 0.0f, 0.0f, 0.0f};

#pragma unroll
    for (int i = 0; i < 2; i++) {
        gload16(kp[i], Ks[0] + (i * 256 + w * 64) * 8);
        gload16(vp[i], Vs[0] + (i * 256 + w * 64) * 8);
    }

    for (int kt = 0; kt <= qt; kt++) {
        const int buf = kt & 1;
        __syncthreads();
        if (kt < qt) {
#pragma unroll
            for (int i = 0; i < 2; i++) {
                gload16(kp[i] + (size_t)(kt + 1) * 64 * C3,
                        Ks[buf ^ 1] + (i * 256 + w * 64) * 8);
                gload16(vp[i] + (kt + 1) * 64,
                        Vs[buf ^ 1] + (i * 256 + w * 64) * 8);
            }
        }

        f32x4 s4[4];
        __builtin_amdgcn_s_setprio(1);
#pragma unroll
        for (int nt = 0; nt < 4; nt++) {
            bf16x8 kf0 = *(const bf16x8*)((const char*)Ks[buf] + offK[0][nt]);
            bf16x8 kf1 = *(const bf16x8*)((const char*)Ks[buf] + offK[1][nt]);
            f32x4 z = {};
            z = MFMA16(qf0, kf0, z);
            z = MFMA16(qf1, kf1, z);
            s4[nt] = z;
        }
        __builtin_amdgcn_s_setprio(0);

        const bool diag = (kt == qt);
        const int myrow = w * 16 + quad * 4;
#pragma unroll
        for (int nt = 0; nt < 4; nt++) {
            const int col = nt * 16 + l16;
#pragma unroll
            for (int r = 0; r < 4; r++) {
                float p = exp2f(s4[nt][r]);
                if (diag && col > myrow + r) p = 0.0f;
                lpart[r] += p;
                Pw[w][(quad * 4 + r) * 72 + col] = __float2bfloat16(p);
            }
        }

        asm volatile("s_waitcnt lgkmcnt(0)" ::: "memory");

        bf16x8 pf0 = *(const bf16x8*)(&Pw[w][l16 * 72 + quad * 8]);
        bf16x8 pf1 = *(const bf16x8*)(&Pw[w][l16 * 72 + 32 + quad * 8]);
        __builtin_amdgcn_s_setprio(1);
#pragma unroll
        for (int dt = 0; dt < 4; dt++) {
            bf16x8 vf0 = *(const bf16x8*)((const char*)Vs[buf] + offK[0][dt]);
            bf16x8 vf1 = *(const bf16x8*)((const char*)Vs[buf] + offK[1][dt]);
            oacc[dt] = MFMA16(pf0, vf0, oacc[dt]);
            oacc[dt] = MFMA16(pf1, vf1, oacc[dt]);
        }
        __builtin_amdgcn_s_setprio(0);
    }

#pragma unroll
    for (int off = 1; off < 16; off <<= 1)
#pragma unroll
        for (int r = 0; r < 4; r++)
            lpart[r] += __shfl_xor(lpart[r], off, 64);

    float rl[4];
#pragma unroll
    for (int r = 0; r < 4; r++) rl[r] = 1.0f / lpart[r];
#pragma unroll
    for (int dt = 0; dt < 4; dt++)
#pragma unroll
        for (int r = 0; r < 4; r++) {
            const int row = q0 + w * 16 + quad * 4 + r;
            outp[(size_t)(b * T + row) * 1024 + h * 64 + dt * 16 + l16] =
                __float2bfloat16(oacc[dt][r] * rl[r]);
        }
}

// --------------------------------- launcher --------------------------------
extern "C" void kernel_launch(void* const* d_in, const int* in_sizes, int n_in,
                              void* d_out, int out_size, void* d_ws, size_t ws_size,
                              hipStream_t stream) {
    const float* x     = (const float*)d_in[0];
    const float* Wqkv  = (const float*)d_in[1];
    const float* Wo    = (const float*)d_in[2];
    const float* b_o   = (const float*)d_in[3];
    const float* g1    = (const float*)d_in[4];
    const float* beta1 = (const float*)d_in[5];
    const float* g2    = (const float*)d_in[6];
    const float* beta2 = (const float*)d_in[7];
    const float* Wff1  = (const float*)d_in[8];
    const float* bff1  = (const float*)d_in[9];
    const float* Wff2  = (const float*)d_in[10];
    const float* bff2  = (const float*)d_in[11];

    char* ws = (char*)d_ws;
    size_t off = 0;
    auto alloc = [&](size_t bytes) {
        void* p = ws + off;
        off += (bytes + 255) & ~(size_t)255;
        return p;
    };
    __hip_bfloat16* Wqkv_t = (__hip_bfloat16*)alloc(3072ULL * 1024 * 2);
    __hip_bfloat16* Wo_t   = (__hip_bfloat16*)alloc(1024ULL * 1024 * 2);
    __hip_bfloat16* Wff1_t = (__hip_bfloat16*)alloc(4096ULL * 1024 * 2);
    __hip_bfloat16* Wff2_t = (__hip_bfloat16*)alloc(1024ULL * 4096 * 2);
    __hip_bfloat16* h_bf   = (__hip_bfloat16*)alloc(4096ULL * 1024 * 2);
    __hip_bfloat16* qkv_bf = (__hip_bfloat16*)alloc(4096ULL * 3072 * 2);
    __hip_bfloat16* att_bf = (__hip_bfloat16*)alloc(4096ULL * 1024 * 2);
    float*          x2     = (float*)alloc(4096ULL * 1024 * 4);
    float*          parts  = (float*)alloc(4ULL * 4096 * 1024 * 4);  // split-K
    __hip_bfloat16* ff1_bf = qkv_bf;              // dead by FF time
    __hip_bfloat16* vt     = (__hip_bfloat16*)x2; // dead before Wo-gemm writes x2

    tconv_all<<<6144, dim3(32, 8), 0, stream>>>(Wqkv, Wqkv_t, Wo, Wo_t,
                                                Wff1, Wff1_t, Wff2, Wff2_t);

    ln_k<<<4096, 256, 0, stream>>>(x, g1, beta1, h_bf);
    gemm256_k<0, 0, 0><<<dim3(3072 / 256, 4096 / 256, 1), 512, 0, stream>>>(
        h_bf, Wqkv_t, nullptr, qkv_bf, 4096, 3072, 1024, 1024);
    vtrans_k<<<dim3(32, 32), dim3(64, 4), 0, stream>>>(qkv_bf, vt);
    attn_k<<<dim3(32, 32), 256, 0, stream>>>(qkv_bf, vt, att_bf);
    gemm6464_k<1, 0, 1, 0><<<dim3(1024 / 64, 4096 / 64), 256, 0, stream>>>(
        att_bf, Wo_t, b_o, x, x2, 4096, 1024, 1024);
    ln_k<<<4096, 256, 0, stream>>>(x2, g2, beta2, h_bf);
    gemm256_k<1, 1, 0><<<dim3(4096 / 256, 4096 / 256, 1), 512, 0, stream>>>(
        h_bf, Wff1_t, bff1, ff1_bf, 4096, 4096, 1024, 1024);
    gemm256_k<0, 0, 1><<<dim3(1024 / 256, 4096 / 256, 4), 512, 0, stream>>>(
        ff1_bf, Wff2_t, nullptr, parts, 4096, 1024, 4096, 1024);
    reduce4_k<<<4096, 256, 0, stream>>>(parts, bff2, x2, (float*)d_out);
}

// Round 11
// 307.737 us; speedup vs baseline: 1.0492x; 1.0492x over previous
//
#include <hip/hip_runtime.h>
#include <hip/hip_bf16.h>
#include <stdint.h>

// ---------------------------------------------------------------------------
// TransformerDecoderBlock on MI355X (gfx950).  B=2, T=2048, C=1024, H=16, hd=64.
// R16 (best, 307.8us): gemm256_k 8-phase for qkv/FF1; gemm6464_k for Wo/FF2.
// R17: 128^2 phase-sched = thin phases, neutral-loss. Reverted.
// R18: FF2 split-K4 via gemm256 FAILED (+15us): counters showed gemm256 runs
//      ~650 TF (53us for 34.4 GFLOP) -- same as ALL structures this session;
//      the split GEMM matched gemm6464 and reduce4_k (+15us) was pure loss.
//      Universal ~650 TF plateau = barrier/latency stalls at 1-2 blk/CU;
//      2-dbuf vmcnt windows provably can't widen (odd-tile B stages land
//      2-3 phases before use).
// R19: revert to R16 wiring exactly (+ neutral attn setprio). Bank 307.8.
// ---------------------------------------------------------------------------

typedef __attribute__((ext_vector_type(8))) short bf16x8;   // 8 bf16 in 4 VGPRs
typedef __attribute__((ext_vector_type(4))) float f32x4;

#define MFMA16(a, b, c) __builtin_amdgcn_mfma_f32_16x16x32_bf16((a), (b), (c), 0, 0, 0)

__device__ __forceinline__ void gload16(const void* g, void* l) {
    __builtin_amdgcn_global_load_lds(
        (const __attribute__((address_space(1))) char*)g,
        (__attribute__((address_space(3))) char*)l, 16, 0, 0);
}

// XCD-aware remap: contiguous chunk of work per XCD (XCD = dispatch id % 8).
__device__ __forceinline__ int xcd_swizzle(int flat, int nblk) {
    if ((nblk & 7) == 0) {
        const int per = nblk >> 3;
        flat = (flat & 7) * per + (flat >> 3);
    }
    return flat;
}

// ---------------- merged transpose + fp32->bf16 for all 4 weights -----------
__global__ __launch_bounds__(256) void tconv_all(
    const float* __restrict__ w0, __hip_bfloat16* __restrict__ o0,   // 1024x3072
    const float* __restrict__ w1, __hip_bfloat16* __restrict__ o1,   // 1024x1024
    const float* __restrict__ w2, __hip_bfloat16* __restrict__ o2,   // 1024x4096
    const float* __restrict__ w3, __hip_bfloat16* __restrict__ o3) { // 4096x1024
    __shared__ float tile[64][33];                  // [k][n]
    const int f = blockIdx.x;
    const float* in; __hip_bfloat16* out; int K, N, nx, t;
    if (f < 1536)      { in = w0; out = o0; K = 1024; N = 3072; nx = 96;  t = f; }
    else if (f < 2048) { in = w1; out = o1; K = 1024; N = 1024; nx = 32;  t = f - 1536; }
    else if (f < 4096) { in = w2; out = o2; K = 1024; N = 4096; nx = 128; t = f - 2048; }
    else               { in = w3; out = o3; K = 4096; N = 1024; nx = 32;  t = f - 4096; }
    const int n0 = (t % nx) * 32, k0 = (t / nx) * 64;
    const int tx = threadIdx.x, ty = threadIdx.y;   // block (32, 8)
#pragma unroll
    for (int i = 0; i < 8; i++)
        tile[i * 8 + ty][tx] = in[(size_t)(k0 + i * 8 + ty) * N + n0 + tx];
    __syncthreads();
    for (int i = ty; i < 32; i += 8) {
        const unsigned short lo =
            __bfloat16_as_ushort(__float2bfloat16(tile[2 * tx][i]));
        const unsigned short hi =
            __bfloat16_as_ushort(__float2bfloat16(tile[2 * tx + 1][i]));
        *(uint32_t*)(out + (size_t)(n0 + i) * K + k0 + 2 * tx) =
            ((uint32_t)hi << 16) | lo;
    }
}

// --------------------------------- layernorm -------------------------------
__global__ __launch_bounds__(256) void ln_k(const float* __restrict__ x,
                                            const float* __restrict__ g,
                                            const float* __restrict__ beta,
                                            __hip_bfloat16* __restrict__ out) {
    const int row = blockIdx.x;
    const int tid = threadIdx.x;
    float4 v = ((const float4*)(x + (size_t)row * 1024))[tid];
    float s  = v.x + v.y + v.z + v.w;
    float s2 = v.x * v.x + v.y * v.y + v.z * v.z + v.w * v.w;
    for (int off = 1; off < 64; off <<= 1) {
        s  += __shfl_xor(s,  off, 64);
        s2 += __shfl_xor(s2, off, 64);
    }
    __shared__ float ss[4], ss2[4];
    const int w = tid >> 6, lane = tid & 63;
    if (lane == 0) { ss[w] = s; ss2[w] = s2; }
    __syncthreads();
    s  = ss[0] + ss[1] + ss[2] + ss[3];
    s2 = ss2[0] + ss2[1] + ss2[2] + ss2[3];
    const float mu  = s * (1.0f / 1024.0f);
    const float var = s2 * (1.0f / 1024.0f) - mu * mu;
    const float rs  = rsqrtf(var + 1e-5f);
    float4 gv = ((const float4*)g)[tid];
    float4 bv = ((const float4*)beta)[tid];
    __hip_bfloat16* o = out + (size_t)row * 1024 + tid * 4;
    o[0] = __float2bfloat16((v.x - mu) * rs * gv.x + bv.x);
    o[1] = __float2bfloat16((v.y - mu) * rs * gv.y + bv.y);
    o[2] = __float2bfloat16((v.z - mu) * rs * gv.z + bv.z);
    o[3] = __float2bfloat16((v.w - mu) * rs * gv.w + bv.w);
}

// ----------- 8-phase GEMM, BM=BN=256 BK=64, 512 threads, 2x4 waves ----------
// [R16 proven -- exact]
template <int BIAS, int RELU>
__global__ __launch_bounds__(512, 2) void gemm256_k(const __hip_bfloat16* __restrict__ A,
                                                    const __hip_bfloat16* __restrict__ Bt,
                                                    const float* __restrict__ bias,
                                                    __hip_bfloat16* __restrict__ out,
                                                    int M, int N, int K) {
    __align__(16) __shared__ __hip_bfloat16 As[2][2][128 * 64];  // [dbuf][half]
    __align__(16) __shared__ __hip_bfloat16 Bs[2][2][128 * 64];

    const int tid  = threadIdx.x;
    const int lane = tid & 63, w = tid >> 6;        // 8 waves
    const int wm = w >> 2, wn = w & 3;              // 2(M) x 4(N)
    const int nbx = gridDim.x;
    const int flat = xcd_swizzle(blockIdx.y * nbx + blockIdx.x, nbx * gridDim.y);
    const int m0 = (flat / nbx) * 256, n0 = (flat % nbx) * 256;
    const int l16 = lane & 15, quad = lane >> 4;

    const int srw = lane >> 3;                 // 0..7
    const int scn = ((lane & 7) - srw) & 7;    // swizzled source chunk

    const __hip_bfloat16* gA[2][2];
    const __hip_bfloat16* gB[2][2];
#pragma unroll
    for (int h = 0; h < 2; h++)
#pragma unroll
        for (int i = 0; i < 2; i++) {
            const int r = h * 128 + i * 64 + w * 8 + srw;
            gA[h][i] = A  + (size_t)(m0 + r) * K + scn * 8;
            gB[h][i] = Bt + (size_t)(n0 + r) * K + scn * 8;
        }

    int offA[2][4], offB[2][2];
#pragma unroll
    for (int s = 0; s < 2; s++) {
#pragma unroll
        for (int t = 0; t < 4; t++) {
            const int r = t * 16 + l16;
            offA[s][t] = (r * 8 + ((s * 4 + quad + (r & 7)) & 7)) * 16;
        }
#pragma unroll
        for (int t = 0; t < 2; t++) {
            const int r = (wn & 1) * 64 + t * 16 + l16;
            offB[s][t] = (r * 8 + ((s * 4 + quad + (r & 7)) & 7)) * 16;
        }
    }
    const char* AsW = (const char*)&As[0][wm][0];       // +D*32768 +MH*8192
    const char* BsW = (const char*)&Bs[0][wn >> 1][0];  // +D*32768 +NH*4096

    f32x4 acc[8][4] = {};
    bf16x8 a[2][4], b[2][2];

    const int NT = K >> 6;   // K-tiles; K=1024 -> 16 (even, >=2)

#define STG_A(ST, SH, D)                                                      \
    do { if ((ST) < NT) {                                                     \
        _Pragma("unroll") for (int i = 0; i < 2; i++)                         \
            gload16(gA[SH][i] + (size_t)(ST) * 64,                            \
                    &As[D][SH][(i * 64 + w * 8) * 64]);                       \
    } } while (0)
#define STG_B(ST, SH, D)                                                      \
    do { if ((ST) < NT) {                                                     \
        _Pragma("unroll") for (int i = 0; i < 2; i++)                         \
            gload16(gB[SH][i] + (size_t)(ST) * 64,                            \
                    &Bs[D][SH][(i * 64 + w * 8) * 64]);                       \
    } } while (0)
#define VM_NONE do {} while (0)
#define VM_P(X)                                                               \
    do { if ((X) < NT) asm volatile("s_waitcnt vmcnt(2)" ::: "memory");       \
         else          asm volatile("s_waitcnt vmcnt(0)" ::: "memory");       \
    } while (0)

#define PH(RDA, MH, RDB, NH, D, STG, VM)                                      \
    do {                                                                      \
        if (RDA) {                                                            \
            _Pragma("unroll") for (int s = 0; s < 2; s++)                     \
            _Pragma("unroll") for (int t = 0; t < 4; t++)                     \
                a[s][t] = *(const bf16x8*)(AsW + (D) * 32768 + (MH) * 8192 +  \
                                           offA[s][t]);                       \
        }                                                                     \
        if (RDB) {                                                            \
            _Pragma("unroll") for (int s = 0; s < 2; s++)                     \
            _Pragma("unroll") for (int t = 0; t < 2; t++)                     \
                b[s][t] = *(const bf16x8*)(BsW + (D) * 32768 + (NH) * 4096 +  \
                                           offB[s][t]);                       \
        }                                                                     \
        STG;                                                                  \
        __builtin_amdgcn_s_barrier();                                         \
        asm volatile("" ::: "memory");                                        \
        __builtin_amdgcn_s_setprio(1);                                        \
        _Pragma("unroll") for (int s = 0; s < 2; s++)                         \
        _Pragma("unroll") for (int ti = 0; ti < 4; ti++)                      \
        _Pragma("unroll") for (int tj = 0; tj < 2; tj++)                      \
            acc[(MH) * 4 + ti][(NH) * 2 + tj] =                               \
                MFMA16(a[s][ti], b[s][tj], acc[(MH) * 4 + ti][(NH) * 2 + tj]);\
        __builtin_amdgcn_s_setprio(0);                                        \
        VM;                                                                   \
        __builtin_amdgcn_s_barrier();                                         \
        asm volatile("" ::: "memory");                                        \
    } while (0)

    STG_A(0, 0, 0); STG_A(0, 1, 0); STG_B(0, 0, 0); STG_B(0, 1, 0);
    STG_A(1, 0, 1);
    asm volatile("s_waitcnt vmcnt(2)" ::: "memory");
    __builtin_amdgcn_s_barrier();
    asm volatile("" ::: "memory");

    for (int T = 0; T < NT; T += 2) {
        PH(1, 0, 1, 0, 0, STG_A(T + 1, 1, 1), VM_NONE);     // p0: q(0,0)
        PH(0, 0, 1, 1, 0, STG_B(T + 1, 0, 1), VM_NONE);     // p1: q(0,1)
        PH(1, 1, 0, 1, 0, STG_B(T + 1, 1, 1), VM_NONE);     // p2: q(1,1)
        PH(0, 1, 1, 0, 0, STG_A(T + 2, 0, 0), VM_P(T + 2)); // p3: q(1,0)
        PH(1, 0, 1, 0, 1, STG_A(T + 2, 1, 0), VM_NONE);     // p4: q(0,0)
        PH(0, 0, 1, 1, 1, STG_B(T + 2, 0, 0), VM_NONE);     // p5: q(0,1)
        PH(1, 1, 0, 1, 1, STG_B(T + 2, 1, 0), VM_NONE);     // p6: q(1,1)
        PH(0, 1, 1, 0, 1, STG_A(T + 3, 0, 1), VM_P(T + 3)); // p7: q(1,0)
    }
#undef PH
#undef VM_P
#undef VM_NONE
#undef STG_B
#undef STG_A

#pragma unroll
    for (int mt = 0; mt < 8; mt++)
#pragma unroll
        for (int nt = 0; nt < 4; nt++) {
            const int row = m0 + wm * 128 + mt * 16 + quad * 4;
            const int col = n0 + wn * 64 + nt * 16 + l16;
            const float bv = BIAS ? bias[col] : 0.0f;
#pragma unroll
            for (int r = 0; r < 4; r++) {
                float v = acc[mt][nt][r] + bv;
                if (RELU) v = v > 0.0f ? v : 0.0f;
                out[(size_t)(row + r) * N + col] = __float2bfloat16(v);
            }
        }
}

// ------------------- GEMM, BM=64 BN=64 BK=64, dbuf 1-barrier -----------------
// For N=1024 outputs: grid (N/64)x(M/64) = 1024 blocks -> 4 blocks/CU. [proven]
template <int BIAS, int RELU, int RESID, int OUTBF>
__global__ __launch_bounds__(256, 4) void gemm6464_k(const __hip_bfloat16* __restrict__ A,
                                                     const __hip_bfloat16* __restrict__ Bt,
                                                     const float* __restrict__ bias,
                                                     const float* __restrict__ resid,
                                                     void* __restrict__ out,
                                                     int M, int N, int K) {
    __align__(16) __shared__ __hip_bfloat16 As[2][64 * 64];
    __align__(16) __shared__ __hip_bfloat16 Bs[2][64 * 64];

    const int tid  = threadIdx.x;
    const int lane = tid & 63, w = tid >> 6;
    const int wm = w >> 1, wn = w & 1;             // 2x2 wave grid of 32x32
    const int nbx = gridDim.x;
    const int flat = xcd_swizzle(blockIdx.y * nbx + blockIdx.x, nbx * gridDim.y);
    const int m0 = (flat / nbx) * 64, n0 = (flat % nbx) * 64;
    const int l16 = lane & 15, quad = lane >> 4;

    const int srw = lane >> 3;
    const int scn = ((lane & 7) - srw) & 7;

    const __hip_bfloat16* ga[2];
    const __hip_bfloat16* gb[2];
#pragma unroll
    for (int i = 0; i < 2; i++) {
        const int row = i * 32 + w * 8 + srw;
        ga[i] = A  + (size_t)(m0 + row) * K + scn * 8;
        gb[i] = Bt + (size_t)(n0 + row) * K + scn * 8;
    }

    int offA[2][2], offB[2][2];
#pragma unroll
    for (int s = 0; s < 2; s++)
#pragma unroll
        for (int t = 0; t < 2; t++) {
            const int rA = wm * 32 + t * 16 + l16;
            offA[s][t] = (rA * 8 + ((s * 4 + quad + (rA & 7)) & 7)) * 16;
            const int rB = wn * 32 + t * 16 + l16;
            offB[s][t] = (rB * 8 + ((s * 4 + quad + (rB & 7)) & 7)) * 16;
        }

    f32x4 acc[2][2] = {};

#pragma unroll
    for (int i = 0; i < 2; i++) {
        gload16(ga[i], As[0] + (i * 256 + w * 64) * 8);
        gload16(gb[i], Bs[0] + (i * 256 + w * 64) * 8);
        ga[i] += 64; gb[i] += 64;
    }

    const int niter = K >> 6;
    for (int it = 0; it < niter; it++) {
        const int buf = it & 1;
        __syncthreads();   // drains prefetch into buf
        if (it + 1 < niter) {
#pragma unroll
            for (int i = 0; i < 2; i++) {
                gload16(ga[i], As[buf ^ 1] + (i * 256 + w * 64) * 8);
                gload16(gb[i], Bs[buf ^ 1] + (i * 256 + w * 64) * 8);
                ga[i] += 64; gb[i] += 64;
            }
        }

#pragma unroll
        for (int s = 0; s < 2; s++) {
            bf16x8 af[2], bfr[2];
#pragma unroll
            for (int t = 0; t < 2; t++) {
                af[t]  = *(const bf16x8*)((const char*)As[buf] + offA[s][t]);
                bfr[t] = *(const bf16x8*)((const char*)Bs[buf] + offB[s][t]);
            }
#pragma unroll
            for (int mt = 0; mt < 2; mt++)
#pragma unroll
                for (int nt = 0; nt < 2; nt++)
                    acc[mt][nt] = MFMA16(af[mt], bfr[nt], acc[mt][nt]);
        }
    }

#pragma unroll
    for (int mt = 0; mt < 2; mt++)
#pragma unroll
        for (int nt = 0; nt < 2; nt++) {
            const int row = m0 + wm * 32 + mt * 16 + quad * 4;
            const int col = n0 + wn * 32 + nt * 16 + l16;
            const float bv = BIAS ? bias[col] : 0.0f;
#pragma unroll
            for (int r = 0; r < 4; r++) {
                float v = acc[mt][nt][r] + bv;
                if (RELU) v = v > 0.0f ? v : 0.0f;
                const size_t idx = (size_t)(row + r) * N + col;
                if (RESID) v += resid[idx];
                if (OUTBF) ((__hip_bfloat16*)out)[idx] = __float2bfloat16(v);
                else       ((float*)out)[idx] = v;
            }
        }
}

// ----------------------- V transpose: qkv -> Vt[bh][d][T] -------------------
__global__ __launch_bounds__(256) void vtrans_k(const __hip_bfloat16* __restrict__ qkv,
                                                __hip_bfloat16* __restrict__ vt) {
    const int T = 2048, C3 = 3072;
    const int bh = blockIdx.y, b = bh >> 4, h = bh & 15;
    const int t0 = blockIdx.x * 64;
    const int tx = threadIdx.x, ty = threadIdx.y;   // block (64, 4)
    __shared__ __hip_bfloat16 tile[64][65];
#pragma unroll
    for (int j = 0; j < 16; j++) {
        const int tl = ty * 16 + j;
        tile[tl][tx] = qkv[(size_t)(b * T + t0 + tl) * C3 + 2048 + h * 64 + tx];
    }
    __syncthreads();
#pragma unroll
    for (int j = 0; j < 16; j++) {
        const int d = ty * 16 + j;
        vt[((size_t)bh * 64 + d) * 2048 + t0 + tx] = tile[tx][d];
    }
}

// ------------------------------ flash attention -----------------------------
__global__ __launch_bounds__(256, 3) void attn_k(const __hip_bfloat16* __restrict__ qkv,
                                                 const __hip_bfloat16* __restrict__ vt,
                                                 __hip_bfloat16* __restrict__ outp) {
    const int T = 2048, C3 = 3072;
    const int bh = blockIdx.x, b = bh >> 4, h = bh & 15;
    const int qt = 31 - blockIdx.y;           // heavy q-tiles dispatched first
    const int q0 = qt * 64;
    const int tid = threadIdx.x, lane = tid & 63, w = tid >> 6;
    const int l16 = lane & 15, quad = lane >> 4;

    __align__(16) __shared__ __hip_bfloat16 Ks[2][64 * 64];   // swizzled [key][d]
    __align__(16) __shared__ __hip_bfloat16 Vs[2][64 * 64];   // swizzled [d][key]
    __align__(16) __shared__ __hip_bfloat16 Pw[4][16 * 72];   // per-wave P

    const float sc = 0.125f * 1.44269504f;
    bf16x8 qf0, qf1;
    {
        const __hip_bfloat16* qp =
            qkv + (size_t)(b * T + q0 + w * 16 + l16) * C3 + h * 64;
        bf16x8 a = *(const bf16x8*)(qp + quad * 8);
        bf16x8 c = *(const bf16x8*)(qp + 32 + quad * 8);
#pragma unroll
        for (int i = 0; i < 8; i++) {
            union { unsigned int u; float f; } ua, uc;
            ua.u = ((unsigned int)(unsigned short)a[i]) << 16;
            uc.u = ((unsigned int)(unsigned short)c[i]) << 16;
            qf0[i] = (short)(__bfloat16_as_ushort(__float2bfloat16(ua.f * sc)));
            qf1[i] = (short)(__bfloat16_as_ushort(__float2bfloat16(uc.f * sc)));
        }
    }

    const int srw = lane >> 3;
    const int scn = ((lane & 7) - srw) & 7;
    const __hip_bfloat16* kp[2];
    const __hip_bfloat16* vp[2];
#pragma unroll
    for (int i = 0; i < 2; i++) {
        const int row = i * 32 + w * 8 + srw;
        kp[i] = qkv + (size_t)(b * T + row) * C3 + 1024 + h * 64 + scn * 8;
        vp[i] = vt + ((size_t)bh * 64 + row) * 2048 + scn * 8;
    }

    int offK[2][4];
#pragma unroll
    for (int s = 0; s < 2; s++)
#pragma unroll
        for (int t = 0; t < 4; t++) {
            const int rr = t * 16 + l16;
            offK[s][t] = (rr * 8 + ((s * 4 + quad + (rr & 7)) & 7)) * 16;
        }

    f32x4 oacc[4] = {};
    float lpart[4] = {0.0f, 0.0f, 0.0f, 0.0f};

#pragma unroll
    for (int i = 0; i < 2; i++) {
        gload16(kp[i], Ks[0] + (i * 256 + w * 64) * 8);
        gload16(vp[i], Vs[0] + (i * 256 + w * 64) * 8);
    }

    for (int kt = 0; kt <= qt; kt++) {
        const int buf = kt & 1;
        __syncthreads();
        if (kt < qt) {
#pragma unroll
            for (int i = 0; i < 2; i++) {
                gload16(kp[i] + (size_t)(kt + 1) * 64 * C3,
                        Ks[buf ^ 1] + (i * 256 + w * 64) * 8);
                gload16(vp[i] + (kt + 1) * 64,
                        Vs[buf ^ 1] + (i * 256 + w * 64) * 8);
            }
        }

        f32x4 s4[4];
        __builtin_amdgcn_s_setprio(1);
#pragma unroll
        for (int nt = 0; nt < 4; nt++) {
            bf16x8 kf0 = *(const bf16x8*)((const char*)Ks[buf] + offK[0][nt]);
            bf16x8 kf1 = *(const bf16x8*)((const char*)Ks[buf] + offK[1][nt]);
            f32x4 z = {};
            z = MFMA16(qf0, kf0, z);
            z = MFMA16(qf1, kf1, z);
            s4[nt] = z;
        }
        __builtin_amdgcn_s_setprio(0);

        const bool diag = (kt == qt);
        const int myrow = w * 16 + quad * 4;
#pragma unroll
        for (int nt = 0; nt < 4; nt++) {
            const int col = nt * 16 + l16;
#pragma unroll
            for (int r = 0; r < 4; r++) {
                float p = exp2f(s4[nt][r]);
                if (diag && col > myrow + r) p = 0.0f;
                lpart[r] += p;
                Pw[w][(quad * 4 + r) * 72 + col] = __float2bfloat16(p);
            }
        }

        asm volatile("s_waitcnt lgkmcnt(0)" ::: "memory");

        bf16x8 pf0 = *(const bf16x8*)(&Pw[w][l16 * 72 + quad * 8]);
        bf16x8 pf1 = *(const bf16x8*)(&Pw[w][l16 * 72 + 32 + quad * 8]);
        __builtin_amdgcn_s_setprio(1);
#pragma unroll
        for (int dt = 0; dt < 4; dt++) {
            bf16x8 vf0 = *(const bf16x8*)((const char*)Vs[buf] + offK[0][dt]);
            bf16x8 vf1 = *(const bf16x8*)((const char*)Vs[buf] + offK[1][dt]);
            oacc[dt] = MFMA16(pf0, vf0, oacc[dt]);
            oacc[dt] = MFMA16(pf1, vf1, oacc[dt]);
        }
        __builtin_amdgcn_s_setprio(0);
    }

#pragma unroll
    for (int off = 1; off < 16; off <<= 1)
#pragma unroll
        for (int r = 0; r < 4; r++)
            lpart[r] += __shfl_xor(lpart[r], off, 64);

    float rl[4];
#pragma unroll
    for (int r = 0; r < 4; r++) rl[r] = 1.0f / lpart[r];
#pragma unroll
    for (int dt = 0; dt < 4; dt++)
#pragma unroll
        for (int r = 0; r < 4; r++) {
            const int row = q0 + w * 16 + quad * 4 + r;
            outp[(size_t)(b * T + row) * 1024 + h * 64 + dt * 16 + l16] =
                __float2bfloat16(oacc[dt][r] * rl[r]);
        }
}

// --------------------------------- launcher --------------------------------
extern "C" void kernel_launch(void* const* d_in, const int* in_sizes, int n_in,
                              void* d_out, int out_size, void* d_ws, size_t ws_size,
                              hipStream_t stream) {
    const float* x     = (const float*)d_in[0];
    const float* Wqkv  = (const float*)d_in[1];
    const float* Wo    = (const float*)d_in[2];
    const float* b_o   = (const float*)d_in[3];
    const float* g1    = (const float*)d_in[4];
    const float* beta1 = (const float*)d_in[5];
    const float* g2    = (const float*)d_in[6];
    const float* beta2 = (const float*)d_in[7];
    const float* Wff1  = (const float*)d_in[8];
    const float* bff1  = (const float*)d_in[9];
    const float* Wff2  = (const float*)d_in[10];
    const float* bff2  = (const float*)d_in[11];

    char* ws = (char*)d_ws;
    size_t off = 0;
    auto alloc = [&](size_t bytes) {
        void* p = ws + off;
        off += (bytes + 255) & ~(size_t)255;
        return p;
    };
    __hip_bfloat16* Wqkv_t = (__hip_bfloat16*)alloc(3072ULL * 1024 * 2);
    __hip_bfloat16* Wo_t   = (__hip_bfloat16*)alloc(1024ULL * 1024 * 2);
    __hip_bfloat16* Wff1_t = (__hip_bfloat16*)alloc(4096ULL * 1024 * 2);
    __hip_bfloat16* Wff2_t = (__hip_bfloat16*)alloc(1024ULL * 4096 * 2);
    __hip_bfloat16* h_bf   = (__hip_bfloat16*)alloc(4096ULL * 1024 * 2);
    __hip_bfloat16* qkv_bf = (__hip_bfloat16*)alloc(4096ULL * 3072 * 2);
    __hip_bfloat16* att_bf = (__hip_bfloat16*)alloc(4096ULL * 1024 * 2);
    float*          x2     = (float*)alloc(4096ULL * 1024 * 4);
    __hip_bfloat16* ff1_bf = qkv_bf;              // dead by FF time
    __hip_bfloat16* vt     = (__hip_bfloat16*)x2; // dead before Wo-gemm writes x2

    tconv_all<<<6144, dim3(32, 8), 0, stream>>>(Wqkv, Wqkv_t, Wo, Wo_t,
                                                Wff1, Wff1_t, Wff2, Wff2_t);

    ln_k<<<4096, 256, 0, stream>>>(x, g1, beta1, h_bf);
    gemm256_k<0, 0><<<dim3(3072 / 256, 4096 / 256), 512, 0, stream>>>(
        h_bf, Wqkv_t, nullptr, qkv_bf, 4096, 3072, 1024);
    vtrans_k<<<dim3(32, 32), dim3(64, 4), 0, stream>>>(qkv_bf, vt);
    attn_k<<<dim3(32, 32), 256, 0, stream>>>(qkv_bf, vt, att_bf);
    gemm6464_k<1, 0, 1, 0><<<dim3(1024 / 64, 4096 / 64), 256, 0, stream>>>(
        att_bf, Wo_t, b_o, x, x2, 4096, 1024, 1024);
    ln_k<<<4096, 256, 0, stream>>>(x2, g2, beta2, h_bf);
    gemm256_k<1, 1><<<dim3(4096 / 256, 4096 / 256), 512, 0, stream>>>(
        h_bf, Wff1_t, bff1, ff1_bf, 4096, 4096, 1024);
    gemm6464_k<1, 0, 1, 0><<<dim3(1024 / 64, 4096 / 64), 256, 0, stream>>>(
        ff1_bf, Wff2_t, bff2, x2, (float*)d_out, 4096, 1024, 4096);
}

// Round 12
// 303.459 us; speedup vs baseline: 1.0640x; 1.0141x over previous
//
#include <hip/hip_runtime.h>
#include <hip/hip_bf16.h>
#include <stdint.h>

// ---------------------------------------------------------------------------
// TransformerDecoderBlock on MI355X (gfx950).  B=2, T=2048, C=1024, H=16, hd=64.
// R16/R19 (champion, 307.7us): gemm256_k 8-phase (counted vmcnt + setprio +
//      8-wave role-split) for qkv/FF1; gemm6464_k (drain-0, 16 waves/CU) for
//      Wo/FF2; coalesced tconv; attn w/ setprio.
// Failed ledger: counted-vmcnt on 2-phase skeletons (R9/R14), tile geometry
//      (R10/R11/R17), BK=32 swizzle (R12), A-from-global (R13), split-K (R18).
//      All GEMM structures plateau ~650 TF.
// R20: delete vtrans_k -- qkv gemm256_k<VOUT=1> V-blocks (n0>=2048) write
//      vt[bh*64+d][t] directly via per-wave LDS bounce (As/Bs dead after
//      loop; 16KB/wave region; coalesced 256B vt segments); qkv_bf V region
//      no longer written. Epilogue-only change; FF1 uses VOUT=0 instance.
// ---------------------------------------------------------------------------

typedef __attribute__((ext_vector_type(8))) short bf16x8;   // 8 bf16 in 4 VGPRs
typedef __attribute__((ext_vector_type(4))) float f32x4;

#define MFMA16(a, b, c) __builtin_amdgcn_mfma_f32_16x16x32_bf16((a), (b), (c), 0, 0, 0)

__device__ __forceinline__ void gload16(const void* g, void* l) {
    __builtin_amdgcn_global_load_lds(
        (const __attribute__((address_space(1))) char*)g,
        (__attribute__((address_space(3))) char*)l, 16, 0, 0);
}

// XCD-aware remap: contiguous chunk of work per XCD (XCD = dispatch id % 8).
__device__ __forceinline__ int xcd_swizzle(int flat, int nblk) {
    if ((nblk & 7) == 0) {
        const int per = nblk >> 3;
        flat = (flat & 7) * per + (flat >> 3);
    }
    return flat;
}

// ---------------- merged transpose + fp32->bf16 for all 4 weights -----------
__global__ __launch_bounds__(256) void tconv_all(
    const float* __restrict__ w0, __hip_bfloat16* __restrict__ o0,   // 1024x3072
    const float* __restrict__ w1, __hip_bfloat16* __restrict__ o1,   // 1024x1024
    const float* __restrict__ w2, __hip_bfloat16* __restrict__ o2,   // 1024x4096
    const float* __restrict__ w3, __hip_bfloat16* __restrict__ o3) { // 4096x1024
    __shared__ float tile[64][33];                  // [k][n]
    const int f = blockIdx.x;
    const float* in; __hip_bfloat16* out; int K, N, nx, t;
    if (f < 1536)      { in = w0; out = o0; K = 1024; N = 3072; nx = 96;  t = f; }
    else if (f < 2048) { in = w1; out = o1; K = 1024; N = 1024; nx = 32;  t = f - 1536; }
    else if (f < 4096) { in = w2; out = o2; K = 1024; N = 4096; nx = 128; t = f - 2048; }
    else               { in = w3; out = o3; K = 4096; N = 1024; nx = 32;  t = f - 4096; }
    const int n0 = (t % nx) * 32, k0 = (t / nx) * 64;
    const int tx = threadIdx.x, ty = threadIdx.y;   // block (32, 8)
#pragma unroll
    for (int i = 0; i < 8; i++)
        tile[i * 8 + ty][tx] = in[(size_t)(k0 + i * 8 + ty) * N + n0 + tx];
    __syncthreads();
    for (int i = ty; i < 32; i += 8) {
        const unsigned short lo =
            __bfloat16_as_ushort(__float2bfloat16(tile[2 * tx][i]));
        const unsigned short hi =
            __bfloat16_as_ushort(__float2bfloat16(tile[2 * tx + 1][i]));
        *(uint32_t*)(out + (size_t)(n0 + i) * K + k0 + 2 * tx) =
            ((uint32_t)hi << 16) | lo;
    }
}

// --------------------------------- layernorm -------------------------------
__global__ __launch_bounds__(256) void ln_k(const float* __restrict__ x,
                                            const float* __restrict__ g,
                                            const float* __restrict__ beta,
                                            __hip_bfloat16* __restrict__ out) {
    const int row = blockIdx.x;
    const int tid = threadIdx.x;
    float4 v = ((const float4*)(x + (size_t)row * 1024))[tid];
    float s  = v.x + v.y + v.z + v.w;
    float s2 = v.x * v.x + v.y * v.y + v.z * v.z + v.w * v.w;
    for (int off = 1; off < 64; off <<= 1) {
        s  += __shfl_xor(s,  off, 64);
        s2 += __shfl_xor(s2, off, 64);
    }
    __shared__ float ss[4], ss2[4];
    const int w = tid >> 6, lane = tid & 63;
    if (lane == 0) { ss[w] = s; ss2[w] = s2; }
    __syncthreads();
    s  = ss[0] + ss[1] + ss[2] + ss[3];
    s2 = ss2[0] + ss2[1] + ss2[2] + ss2[3];
    const float mu  = s * (1.0f / 1024.0f);
    const float var = s2 * (1.0f / 1024.0f) - mu * mu;
    const float rs  = rsqrtf(var + 1e-5f);
    float4 gv = ((const float4*)g)[tid];
    float4 bv = ((const float4*)beta)[tid];
    __hip_bfloat16* o = out + (size_t)row * 1024 + tid * 4;
    o[0] = __float2bfloat16((v.x - mu) * rs * gv.x + bv.x);
    o[1] = __float2bfloat16((v.y - mu) * rs * gv.y + bv.y);
    o[2] = __float2bfloat16((v.z - mu) * rs * gv.z + bv.z);
    o[3] = __float2bfloat16((v.w - mu) * rs * gv.w + bv.w);
}

// ----------- 8-phase GEMM, BM=BN=256 BK=64, 512 threads, 2x4 waves ----------
// [R16 proven] VOUT=1: blocks with n0>=2048 (qkv V region) write vt[d][t]
// directly (per-wave LDS-bounce transpose) and skip the qkv_bf write.
template <int BIAS, int RELU, int VOUT>
__global__ __launch_bounds__(512, 2) void gemm256_k(const __hip_bfloat16* __restrict__ A,
                                                    const __hip_bfloat16* __restrict__ Bt,
                                                    const float* __restrict__ bias,
                                                    __hip_bfloat16* __restrict__ out,
                                                    __hip_bfloat16* __restrict__ vt,
                                                    int M, int N, int K) {
    __align__(16) __shared__ __hip_bfloat16 As[2][2][128 * 64];  // [dbuf][half]
    __align__(16) __shared__ __hip_bfloat16 Bs[2][2][128 * 64];

    const int tid  = threadIdx.x;
    const int lane = tid & 63, w = tid >> 6;        // 8 waves
    const int wm = w >> 2, wn = w & 3;              // 2(M) x 4(N)
    const int nbx = gridDim.x;
    const int flat = xcd_swizzle(blockIdx.y * nbx + blockIdx.x, nbx * gridDim.y);
    const int m0 = (flat / nbx) * 256, n0 = (flat % nbx) * 256;
    const int l16 = lane & 15, quad = lane >> 4;

    const int srw = lane >> 3;                 // 0..7
    const int scn = ((lane & 7) - srw) & 7;    // swizzled source chunk

    const __hip_bfloat16* gA[2][2];
    const __hip_bfloat16* gB[2][2];
#pragma unroll
    for (int h = 0; h < 2; h++)
#pragma unroll
        for (int i = 0; i < 2; i++) {
            const int r = h * 128 + i * 64 + w * 8 + srw;
            gA[h][i] = A  + (size_t)(m0 + r) * K + scn * 8;
            gB[h][i] = Bt + (size_t)(n0 + r) * K + scn * 8;
        }

    int offA[2][4], offB[2][2];
#pragma unroll
    for (int s = 0; s < 2; s++) {
#pragma unroll
        for (int t = 0; t < 4; t++) {
            const int r = t * 16 + l16;
            offA[s][t] = (r * 8 + ((s * 4 + quad + (r & 7)) & 7)) * 16;
        }
#pragma unroll
        for (int t = 0; t < 2; t++) {
            const int r = (wn & 1) * 64 + t * 16 + l16;
            offB[s][t] = (r * 8 + ((s * 4 + quad + (r & 7)) & 7)) * 16;
        }
    }
    const char* AsW = (const char*)&As[0][wm][0];       // +D*32768 +MH*8192
    const char* BsW = (const char*)&Bs[0][wn >> 1][0];  // +D*32768 +NH*4096

    f32x4 acc[8][4] = {};
    bf16x8 a[2][4], b[2][2];

    const int NT = K >> 6;   // K-tiles; K=1024 -> 16 (even, >=2)

#define STG_A(ST, SH, D)                                                      \
    do { if ((ST) < NT) {                                                     \
        _Pragma("unroll") for (int i = 0; i < 2; i++)                         \
            gload16(gA[SH][i] + (size_t)(ST) * 64,                            \
                    &As[D][SH][(i * 64 + w * 8) * 64]);                       \
    } } while (0)
#define STG_B(ST, SH, D)                                                      \
    do { if ((ST) < NT) {                                                     \
        _Pragma("unroll") for (int i = 0; i < 2; i++)                         \
            gload16(gB[SH][i] + (size_t)(ST) * 64,                            \
                    &Bs[D][SH][(i * 64 + w * 8) * 64]);                       \
    } } while (0)
#define VM_NONE do {} while (0)
#define VM_P(X)                                                               \
    do { if ((X) < NT) asm volatile("s_waitcnt vmcnt(2)" ::: "memory");       \
         else          asm volatile("s_waitcnt vmcnt(0)" ::: "memory");       \
    } while (0)

#define PH(RDA, MH, RDB, NH, D, STG, VM)                                      \
    do {                                                                      \
        if (RDA) {                                                            \
            _Pragma("unroll") for (int s = 0; s < 2; s++)                     \
            _Pragma("unroll") for (int t = 0; t < 4; t++)                     \
                a[s][t] = *(const bf16x8*)(AsW + (D) * 32768 + (MH) * 8192 +  \
                                           offA[s][t]);                       \
        }                                                                     \
        if (RDB) {                                                            \
            _Pragma("unroll") for (int s = 0; s < 2; s++)                     \
            _Pragma("unroll") for (int t = 0; t < 2; t++)                     \
                b[s][t] = *(const bf16x8*)(BsW + (D) * 32768 + (NH) * 4096 +  \
                                           offB[s][t]);                       \
        }                                                                     \
        STG;                                                                  \
        __builtin_amdgcn_s_barrier();                                         \
        asm volatile("" ::: "memory");                                        \
        __builtin_amdgcn_s_setprio(1);                                        \
        _Pragma("unroll") for (int s = 0; s < 2; s++)                         \
        _Pragma("unroll") for (int ti = 0; ti < 4; ti++)                      \
        _Pragma("unroll") for (int tj = 0; tj < 2; tj++)                      \
            acc[(MH) * 4 + ti][(NH) * 2 + tj] =                               \
                MFMA16(a[s][ti], b[s][tj], acc[(MH) * 4 + ti][(NH) * 2 + tj]);\
        __builtin_amdgcn_s_setprio(0);                                        \
        VM;                                                                   \
        __builtin_amdgcn_s_barrier();                                         \
        asm volatile("" ::: "memory");                                        \
    } while (0)

    STG_A(0, 0, 0); STG_A(0, 1, 0); STG_B(0, 0, 0); STG_B(0, 1, 0);
    STG_A(1, 0, 1);
    asm volatile("s_waitcnt vmcnt(2)" ::: "memory");
    __builtin_amdgcn_s_barrier();
    asm volatile("" ::: "memory");

    for (int T = 0; T < NT; T += 2) {
        PH(1, 0, 1, 0, 0, STG_A(T + 1, 1, 1), VM_NONE);     // p0: q(0,0)
        PH(0, 0, 1, 1, 0, STG_B(T + 1, 0, 1), VM_NONE);     // p1: q(0,1)
        PH(1, 1, 0, 1, 0, STG_B(T + 1, 1, 1), VM_NONE);     // p2: q(1,1)
        PH(0, 1, 1, 0, 0, STG_A(T + 2, 0, 0), VM_P(T + 2)); // p3: q(1,0)
        PH(1, 0, 1, 0, 1, STG_A(T + 2, 1, 0), VM_NONE);     // p4: q(0,0)
        PH(0, 0, 1, 1, 1, STG_B(T + 2, 0, 0), VM_NONE);     // p5: q(0,1)
        PH(1, 1, 0, 1, 1, STG_B(T + 2, 1, 0), VM_NONE);     // p6: q(1,1)
        PH(0, 1, 1, 0, 1, STG_A(T + 3, 0, 1), VM_P(T + 3)); // p7: q(1,0)
    }
#undef PH
#undef VM_P
#undef VM_NONE
#undef STG_B
#undef STG_A

    // last phase ended with s_barrier: all waves done reading LDS.
    if (VOUT && n0 >= 2048) {
        // V-block: transpose wave's 128x64 acc into vt[bh*64+d][t].
        const int wrow = m0 + wm * 128;              // within one batch b
        const int wcol = n0 + wn * 64;               // within one head h
        const int bb   = wrow >> 11;
        const int t0   = wrow & 2047;
        const int bh   = bb * 16 + ((wcol - 2048) >> 6);
        // per-wave 16KB LDS region (As: waves 0-3, Bs: waves 4-7)
        __hip_bfloat16* lds =
            ((w < 4) ? (__hip_bfloat16*)As : (__hip_bfloat16*)Bs) +
            (w & 3) * 8192;
        // two passes of 32 cols; [col][136] layout (272B stride: 16B-aligned)
#pragma unroll
        for (int half = 0; half < 2; half++) {
#pragma unroll
            for (int mt = 0; mt < 8; mt++)
#pragma unroll
                for (int nt2 = 0; nt2 < 2; nt2++) {
                    const int nt = half * 2 + nt2;
                    const int c  = nt2 * 16 + l16;          // 0..31
                    const int rl = mt * 16 + quad * 4;
                    ushort4 pk;
                    pk.x = __bfloat16_as_ushort(__float2bfloat16(acc[mt][nt][0]));
                    pk.y = __bfloat16_as_ushort(__float2bfloat16(acc[mt][nt][1]));
                    pk.z = __bfloat16_as_ushort(__float2bfloat16(acc[mt][nt][2]));
                    pk.w = __bfloat16_as_ushort(__float2bfloat16(acc[mt][nt][3]));
                    *(ushort4*)(lds + c * 136 + rl) = pk;
                }
            // compiler orders ds_write -> ds_read via mem deps (same array)
#pragma unroll
            for (int p = 0; p < 8; p++) {
                const int cc = p * 4 + (lane >> 4);         // 0..31
                const int tc = lane & 15;                   // 8-elem t-chunk
                bf16x8 v = *(const bf16x8*)(lds + cc * 136 + tc * 8);
                *(bf16x8*)(vt + (size_t)(bh * 64 + half * 32 + cc) * 2048 +
                           t0 + tc * 8) = v;
            }
            // half=1 rewrites the region; same-wave deps order it.
        }
    } else {
#pragma unroll
        for (int mt = 0; mt < 8; mt++)
#pragma unroll
            for (int nt = 0; nt < 4; nt++) {
                const int row = m0 + wm * 128 + mt * 16 + quad * 4;
                const int col = n0 + wn * 64 + nt * 16 + l16;
                const float bv = BIAS ? bias[col] : 0.0f;
#pragma unroll
                for (int r = 0; r < 4; r++) {
                    float v = acc[mt][nt][r] + bv;
                    if (RELU) v = v > 0.0f ? v : 0.0f;
                    out[(size_t)(row + r) * N + col] = __float2bfloat16(v);
                }
            }
    }
}

// ------------------- GEMM, BM=64 BN=64 BK=64, dbuf 1-barrier -----------------
// For N=1024 outputs: grid (N/64)x(M/64) = 1024 blocks -> 4 blocks/CU. [proven]
template <int BIAS, int RELU, int RESID, int OUTBF>
__global__ __launch_bounds__(256, 4) void gemm6464_k(const __hip_bfloat16* __restrict__ A,
                                                     const __hip_bfloat16* __restrict__ Bt,
                                                     const float* __restrict__ bias,
                                                     const float* __restrict__ resid,
                                                     void* __restrict__ out,
                                                     int M, int N, int K) {
    __align__(16) __shared__ __hip_bfloat16 As[2][64 * 64];
    __align__(16) __shared__ __hip_bfloat16 Bs[2][64 * 64];

    const int tid  = threadIdx.x;
    const int lane = tid & 63, w = tid >> 6;
    const int wm = w >> 1, wn = w & 1;             // 2x2 wave grid of 32x32
    const int nbx = gridDim.x;
    const int flat = xcd_swizzle(blockIdx.y * nbx + blockIdx.x, nbx * gridDim.y);
    const int m0 = (flat / nbx) * 64, n0 = (flat % nbx) * 64;
    const int l16 = lane & 15, quad = lane >> 4;

    const int srw = lane >> 3;
    const int scn = ((lane & 7) - srw) & 7;

    const __hip_bfloat16* ga[2];
    const __hip_bfloat16* gb[2];
#pragma unroll
    for (int i = 0; i < 2; i++) {
        const int row = i * 32 + w * 8 + srw;
        ga[i] = A  + (size_t)(m0 + row) * K + scn * 8;
        gb[i] = Bt + (size_t)(n0 + row) * K + scn * 8;
    }

    int offA[2][2], offB[2][2];
#pragma unroll
    for (int s = 0; s < 2; s++)
#pragma unroll
        for (int t = 0; t < 2; t++) {
            const int rA = wm * 32 + t * 16 + l16;
            offA[s][t] = (rA * 8 + ((s * 4 + quad + (rA & 7)) & 7)) * 16;
            const int rB = wn * 32 + t * 16 + l16;
            offB[s][t] = (rB * 8 + ((s * 4 + quad + (rB & 7)) & 7)) * 16;
        }

    f32x4 acc[2][2] = {};

#pragma unroll
    for (int i = 0; i < 2; i++) {
        gload16(ga[i], As[0] + (i * 256 + w * 64) * 8);
        gload16(gb[i], Bs[0] + (i * 256 + w * 64) * 8);
        ga[i] += 64; gb[i] += 64;
    }

    const int niter = K >> 6;
    for (int it = 0; it < niter; it++) {
        const int buf = it & 1;
        __syncthreads();   // drains prefetch into buf
        if (it + 1 < niter) {
#pragma unroll
            for (int i = 0; i < 2; i++) {
                gload16(ga[i], As[buf ^ 1] + (i * 256 + w * 64) * 8);
                gload16(gb[i], Bs[buf ^ 1] + (i * 256 + w * 64) * 8);
                ga[i] += 64; gb[i] += 64;
            }
        }

#pragma unroll
        for (int s = 0; s < 2; s++) {
            bf16x8 af[2], bfr[2];
#pragma unroll
            for (int t = 0; t < 2; t++) {
                af[t]  = *(const bf16x8*)((const char*)As[buf] + offA[s][t]);
                bfr[t] = *(const bf16x8*)((const char*)Bs[buf] + offB[s][t]);
            }
#pragma unroll
            for (int mt = 0; mt < 2; mt++)
#pragma unroll
                for (int nt = 0; nt < 2; nt++)
                    acc[mt][nt] = MFMA16(af[mt], bfr[nt], acc[mt][nt]);
        }
    }

#pragma unroll
    for (int mt = 0; mt < 2; mt++)
#pragma unroll
        for (int nt = 0; nt < 2; nt++) {
            const int row = m0 + wm * 32 + mt * 16 + quad * 4;
            const int col = n0 + wn * 32 + nt * 16 + l16;
            const float bv = BIAS ? bias[col] : 0.0f;
#pragma unroll
            for (int r = 0; r < 4; r++) {
                float v = acc[mt][nt][r] + bv;
                if (RELU) v = v > 0.0f ? v : 0.0f;
                const size_t idx = (size_t)(row + r) * N + col;
                if (RESID) v += resid[idx];
                if (OUTBF) ((__hip_bfloat16*)out)[idx] = __float2bfloat16(v);
                else       ((float*)out)[idx] = v;
            }
        }
}

// ------------------------------ flash attention -----------------------------
__global__ __launch_bounds__(256, 3) void attn_k(const __hip_bfloat16* __restrict__ qkv,
                                                 const __hip_bfloat16* __restrict__ vt,
                                                 __hip_bfloat16* __restrict__ outp) {
    const int T = 2048, C3 = 3072;
    const int bh = blockIdx.x, b = bh >> 4, h = bh & 15;
    const int qt = 31 - blockIdx.y;           // heavy q-tiles dispatched first
    const int q0 = qt * 64;
    const int tid = threadIdx.x, lane = tid & 63, w = tid >> 6;
    const int l16 = lane & 15, quad = lane >> 4;

    __align__(16) __shared__ __hip_bfloat16 Ks[2][64 * 64];   // swizzled [key][d]
    __align__(16) __shared__ __hip_bfloat16 Vs[2][64 * 64];   // swizzled [d][key]
    __align__(16) __shared__ __hip_bfloat16 Pw[4][16 * 72];   // per-wave P

    const float sc = 0.125f * 1.44269504f;
    bf16x8 qf0, qf1;
    {
        const __hip_bfloat16* qp =
            qkv + (size_t)(b * T + q0 + w * 16 + l16) * C3 + h * 64;
        bf16x8 a = *(const bf16x8*)(qp + quad * 8);
        bf16x8 c = *(const bf16x8*)(qp + 32 + quad * 8);
#pragma unroll
        for (int i = 0; i < 8; i++) {
            union { unsigned int u; float f; } ua, uc;
            ua.u = ((unsigned int)(unsigned short)a[i]) << 16;
            uc.u = ((unsigned int)(unsigned short)c[i]) << 16;
            qf0[i] = (short)(__bfloat16_as_ushort(__float2bfloat16(ua.f * sc)));
            qf1[i] = (short)(__bfloat16_as_ushort(__float2bfloat16(uc.f * sc)));
        }
    }

    const int srw = lane >> 3;
    const int scn = ((lane & 7) - srw) & 7;
    const __hip_bfloat16* kp[2];
    const __hip_bfloat16* vp[2];
#pragma unroll
    for (int i = 0; i < 2; i++) {
        const int row = i * 32 + w * 8 + srw;
        kp[i] = qkv + (size_t)(b * T + row) * C3 + 1024 + h * 64 + scn * 8;
        vp[i] = vt + ((size_t)bh * 64 + row) * 2048 + scn * 8;
    }

    int offK[2][4];
#pragma unroll
    for (int s = 0; s < 2; s++)
#pragma unroll
        for (int t = 0; t < 4; t++) {
            const int rr = t * 16 + l16;
            offK[s][t] = (rr * 8 + ((s * 4 + quad + (rr & 7)) & 7)) * 16;
        }

    f32x4 oacc[4] = {};
    float lpart[4] = {0.0f, 0.0f, 0.0f, 0.0f};

#pragma unroll
    for (int i = 0; i < 2; i++) {
        gload16(kp[i], Ks[0] + (i * 256 + w * 64) * 8);
        gload16(vp[i], Vs[0] + (i * 256 + w * 64) * 8);
    }

    for (int kt = 0; kt <= qt; kt++) {
        const int buf = kt & 1;
        __syncthreads();
        if (kt < qt) {
#pragma unroll
            for (int i = 0; i < 2; i++) {
                gload16(kp[i] + (size_t)(kt + 1) * 64 * C3,
                        Ks[buf ^ 1] + (i * 256 + w * 64) * 8);
                gload16(vp[i] + (kt + 1) * 64,
                        Vs[buf ^ 1] + (i * 256 + w * 64) * 8);
            }
        }

        f32x4 s4[4];
        __builtin_amdgcn_s_setprio(1);
#pragma unroll
        for (int nt = 0; nt < 4; nt++) {
            bf16x8 kf0 = *(const bf16x8*)((const char*)Ks[buf] + offK[0][nt]);
            bf16x8 kf1 = *(const bf16x8*)((const char*)Ks[buf] + offK[1][nt]);
            f32x4 z = {};
            z = MFMA16(qf0, kf0, z);
            z = MFMA16(qf1, kf1, z);
            s4[nt] = z;
        }
        __builtin_amdgcn_s_setprio(0);

        const bool diag = (kt == qt);
        const int myrow = w * 16 + quad * 4;
#pragma unroll
        for (int nt = 0; nt < 4; nt++) {
            const int col = nt * 16 + l16;
#pragma unroll
            for (int r = 0; r < 4; r++) {
                float p = exp2f(s4[nt][r]);
                if (diag && col > myrow + r) p = 0.0f;
                lpart[r] += p;
                Pw[w][(quad * 4 + r) * 72 + col] = __float2bfloat16(p);
            }
        }

        asm volatile("s_waitcnt lgkmcnt(0)" ::: "memory");

        bf16x8 pf0 = *(const bf16x8*)(&Pw[w][l16 * 72 + quad * 8]);
        bf16x8 pf1 = *(const bf16x8*)(&Pw[w][l16 * 72 + 32 + quad * 8]);
        __builtin_amdgcn_s_setprio(1);
#pragma unroll
        for (int dt = 0; dt < 4; dt++) {
            bf16x8 vf0 = *(const bf16x8*)((const char*)Vs[buf] + offK[0][dt]);
            bf16x8 vf1 = *(const bf16x8*)((const char*)Vs[buf] + offK[1][dt]);
            oacc[dt] = MFMA16(pf0, vf0, oacc[dt]);
            oacc[dt] = MFMA16(pf1, vf1, oacc[dt]);
        }
        __builtin_amdgcn_s_setprio(0);
    }

#pragma unroll
    for (int off = 1; off < 16; off <<= 1)
#pragma unroll
        for (int r = 0; r < 4; r++)
            lpart[r] += __shfl_xor(lpart[r], off, 64);

    float rl[4];
#pragma unroll
    for (int r = 0; r < 4; r++) rl[r] = 1.0f / lpart[r];
#pragma unroll
    for (int dt = 0; dt < 4; dt++)
#pragma unroll
        for (int r = 0; r < 4; r++) {
            const int row = q0 + w * 16 + quad * 4 + r;
            outp[(size_t)(b * T + row) * 1024 + h * 64 + dt * 16 + l16] =
                __float2bfloat16(oacc[dt][r] * rl[r]);
        }
}

// --------------------------------- launcher --------------------------------
extern "C" void kernel_launch(void* const* d_in, const int* in_sizes, int n_in,
                              void* d_out, int out_size, void* d_ws, size_t ws_size,
                              hipStream_t stream) {
    const float* x     = (const float*)d_in[0];
    const float* Wqkv  = (const float*)d_in[1];
    const float* Wo    = (const float*)d_in[2];
    const float* b_o   = (const float*)d_in[3];
    const float* g1    = (const float*)d_in[4];
    const float* beta1 = (const float*)d_in[5];
    const float* g2    = (const float*)d_in[6];
    const float* beta2 = (const float*)d_in[7];
    const float* Wff1  = (const float*)d_in[8];
    const float* bff1  = (const float*)d_in[9];
    const float* Wff2  = (const float*)d_in[10];
    const float* bff2  = (const float*)d_in[11];

    char* ws = (char*)d_ws;
    size_t off = 0;
    auto alloc = [&](size_t bytes) {
        void* p = ws + off;
        off += (bytes + 255) & ~(size_t)255;
        return p;
    };
    __hip_bfloat16* Wqkv_t = (__hip_bfloat16*)alloc(3072ULL * 1024 * 2);
    __hip_bfloat16* Wo_t   = (__hip_bfloat16*)alloc(1024ULL * 1024 * 2);
    __hip_bfloat16* Wff1_t = (__hip_bfloat16*)alloc(4096ULL * 1024 * 2);
    __hip_bfloat16* Wff2_t = (__hip_bfloat16*)alloc(1024ULL * 4096 * 2);
    __hip_bfloat16* h_bf   = (__hip_bfloat16*)alloc(4096ULL * 1024 * 2);
    __hip_bfloat16* qkv_bf = (__hip_bfloat16*)alloc(4096ULL * 3072 * 2);
    __hip_bfloat16* att_bf = (__hip_bfloat16*)alloc(4096ULL * 1024 * 2);
    float*          x2     = (float*)alloc(4096ULL * 1024 * 4);
    __hip_bfloat16* ff1_bf = qkv_bf;              // dead by FF time
    __hip_bfloat16* vt     = (__hip_bfloat16*)x2; // dead before Wo-gemm writes x2

    tconv_all<<<6144, dim3(32, 8), 0, stream>>>(Wqkv, Wqkv_t, Wo, Wo_t,
                                                Wff1, Wff1_t, Wff2, Wff2_t);

    ln_k<<<4096, 256, 0, stream>>>(x, g1, beta1, h_bf);
    gemm256_k<0, 0, 1><<<dim3(3072 / 256, 4096 / 256), 512, 0, stream>>>(
        h_bf, Wqkv_t, nullptr, qkv_bf, vt, 4096, 3072, 1024);
    attn_k<<<dim3(32, 32), 256, 0, stream>>>(qkv_bf, vt, att_bf);
    gemm6464_k<1, 0, 1, 0><<<dim3(1024 / 64, 4096 / 64), 256, 0, stream>>>(
        att_bf, Wo_t, b_o, x, x2, 4096, 1024, 1024);
    ln_k<<<4096, 256, 0, stream>>>(x2, g2, beta2, h_bf);
    gemm256_k<1, 1, 0><<<dim3(4096 / 256, 4096 / 256), 512, 0, stream>>>(
        h_bf, Wff1_t, bff1, ff1_bf, nullptr, 4096, 4096, 1024);
    gemm6464_k<1, 0, 1, 0><<<dim3(1024 / 64, 4096 / 64), 256, 0, stream>>>(
        ff1_bf, Wff2_t, bff2, x2, (float*)d_out, 4096, 1024, 4096);
}